// Round 5
// baseline (490.071 us; speedup 1.0000x reference)
//
#include <hip/hip_runtime.h>

#define N_NODES  50000
#define N_EDGES  1600000
#define NODE_DIM 1024
#define HID      128
#define LN_EPS   1e-5f
#define NBUCK    196              // dst>>8 buckets (256 nodes each)
#define SHARD    6250             // N_EDGES / 256
#define MB       391              // row blocks (128 rows each)

typedef float f32x4 __attribute__((ext_vector_type(4)));
typedef __bf16 bf16x8 __attribute__((ext_vector_type(8)));
typedef unsigned short u16x8 __attribute__((ext_vector_type(8)));

__device__ __forceinline__ unsigned short f2bf(float f) {
  __bf16 b = (__bf16)f;
  return __builtin_bit_cast(unsigned short, b);
}
__device__ __forceinline__ unsigned int pkbf(float a, float b) {
  return (unsigned int)f2bf(a) | ((unsigned int)f2bf(b) << 16);
}
__device__ __forceinline__ float bf2f(unsigned short v) {
  return __uint_as_float((unsigned int)v << 16);
}
__device__ __forceinline__ bf16x8 cvt8(const float4 a, const float4 b) {
  union { unsigned int u[4]; bf16x8 v; } t;
  t.u[0] = pkbf(a.x, a.y); t.u[1] = pkbf(a.z, a.w);
  t.u[2] = pkbf(b.x, b.y); t.u[3] = pkbf(b.z, b.w);
  return t.v;
}

__device__ __forceinline__ int scan256_excl(int v, int buf[2][256], int t) {
  int cur = 0;
  buf[0][t] = v;
  __syncthreads();
  for (int off = 1; off < 256; off <<= 1) {
    int nxt = cur ^ 1;
    int s = buf[cur][t];
    if (t >= off) s += buf[cur][t - off];
    buf[nxt][t] = s;
    cur = nxt;
    __syncthreads();
  }
  return buf[cur][t] - v;
}

// ---------------------------------------------------------------------------
// K_PREP: pw -> bf16 pwb; [wl|wr] -> bf16 wcomb[col][256]
// ---------------------------------------------------------------------------
__global__ __launch_bounds__(256) void k_prep(const float* __restrict__ pw,
                                              const float* __restrict__ wl,
                                              const float* __restrict__ wr,
                                              unsigned short* __restrict__ pwb,
                                              unsigned short* __restrict__ wcomb) {
  int i = blockIdx.x * 256 + threadIdx.x;
  if (i < HID * NODE_DIM) {
    pwb[i] = f2bf(pw[i]);
  } else {
    int j = i - HID * NODE_DIM;
    if (j < HID * 256) {
      int c = j >> 8, k = j & 255;
      float v = (k < HID) ? wl[c * HID + k] : wr[c * HID + (k - HID)];
      wcomb[j] = f2bf(v);
    }
  }
}

// ---------------------------------------------------------------------------
// K_PROJ: h = bf16(relu(x @ proj_w^T + proj_b)) — no LDS, no barriers.
// Wave owns 32 rows x 128 cols. Fragments loaded straight to registers.
// ---------------------------------------------------------------------------
__global__ __launch_bounds__(256) void k_proj(const float* __restrict__ x,
                                              const unsigned short* __restrict__ pwb,
                                              const float* __restrict__ pb,
                                              unsigned short* __restrict__ h) {
  const int wave = threadIdx.x >> 6, lane = threadIdx.x & 63;
  const int wr0 = blockIdx.x * 128 + wave * 32;
  const int fr = lane & 15, kg = lane >> 4;

  int r0 = wr0 + fr;       if (r0 > N_NODES - 1) r0 = N_NODES - 1;
  int r1 = wr0 + 16 + fr;  if (r1 > N_NODES - 1) r1 = N_NODES - 1;
  const float* pA0 = x + (size_t)r0 * NODE_DIM + kg * 8;
  const float* pA1 = x + (size_t)r1 * NODE_DIM + kg * 8;
  const unsigned short* pB[8];
#pragma unroll
  for (int n = 0; n < 8; n++)
    pB[n] = pwb + (size_t)(n * 16 + fr) * NODE_DIM + kg * 8;

  f32x4 acc[2][8] = {};

#pragma unroll 2
  for (int k0 = 0; k0 < NODE_DIM; k0 += 32) {
    float4 a00 = *(const float4*)(pA0 + k0);
    float4 a01 = *(const float4*)(pA0 + k0 + 4);
    float4 a10 = *(const float4*)(pA1 + k0);
    float4 a11 = *(const float4*)(pA1 + k0 + 4);
    bf16x8 bfv[8];
#pragma unroll
    for (int n = 0; n < 8; n++) bfv[n] = *(const bf16x8*)(pB[n] + k0);
    bf16x8 af0 = cvt8(a00, a01);
    bf16x8 af1 = cvt8(a10, a11);
#pragma unroll
    for (int n = 0; n < 8; n++) {
      acc[0][n] = __builtin_amdgcn_mfma_f32_16x16x32_bf16(af0, bfv[n], acc[0][n], 0, 0, 0);
      acc[1][n] = __builtin_amdgcn_mfma_f32_16x16x32_bf16(af1, bfv[n], acc[1][n], 0, 0, 0);
    }
  }

  float pbv[8];
#pragma unroll
  for (int n = 0; n < 8; n++) pbv[n] = pb[n * 16 + fr];

#pragma unroll
  for (int m = 0; m < 2; m++) {
#pragma unroll
    for (int i = 0; i < 4; i++) {
      const int row = wr0 + m * 16 + kg * 4 + i;
      if (row < N_NODES) {
#pragma unroll
        for (int n = 0; n < 8; n++) {
          float v = acc[m][n][i] + pbv[n];
          h[(size_t)row * HID + n * 16 + fr] = f2bf(v > 0.f ? v : 0.f);
        }
      }
    }
  }
}

// ---------------------------------------------------------------------------
// CSR build: hist -> scan -> scan -> scatter(packed) -> per-bucket CSR
// ---------------------------------------------------------------------------
__global__ __launch_bounds__(256) void k_hist(const int* __restrict__ ei,
                                              int* __restrict__ counts) {
  __shared__ int bins[NBUCK];
  int t = threadIdx.x;
  if (t < NBUCK) bins[t] = 0;
  __syncthreads();
  int base = blockIdx.x * SHARD;
  for (int i = t; i < SHARD; i += 256)
    atomicAdd(&bins[ei[N_EDGES + base + i] >> 8], 1);
  __syncthreads();
  if (t < NBUCK) counts[t * 256 + blockIdx.x] = bins[t];
}

__global__ __launch_bounds__(256) void k_s1(const int* __restrict__ counts,
                                            int* __restrict__ basem,
                                            int* __restrict__ btot) {
  __shared__ int buf[2][256];
  int t = threadIdx.x, b = blockIdx.x;
  int v = counts[b * 256 + t];
  int excl = scan256_excl(v, buf, t);
  basem[b * 256 + t] = excl;
  if (t == 255) btot[b] = excl + v;
}

__global__ __launch_bounds__(256) void k_s2(const int* __restrict__ btot,
                                            int* __restrict__ bstart) {
  __shared__ int buf[2][256];
  int t = threadIdx.x;
  int v = (t < NBUCK) ? btot[t] : 0;
  int excl = scan256_excl(v, buf, t);
  if (t < NBUCK) bstart[t] = excl;
  if (t == 0) bstart[NBUCK] = N_EDGES;
}

__global__ __launch_bounds__(256) void k_scatter(const int* __restrict__ ei,
                                                 const int* __restrict__ basem,
                                                 const int* __restrict__ bstart,
                                                 unsigned int* __restrict__ bs) {
  __shared__ int cur[NBUCK];
  int t = threadIdx.x;
  if (t < NBUCK) cur[t] = bstart[t] + basem[t * 256 + blockIdx.x];
  __syncthreads();
  int base = blockIdx.x * SHARD;
  for (int i = t; i < SHARD; i += 256) {
    int e = base + i;
    unsigned int src = (unsigned int)ei[e];
    unsigned int dst = (unsigned int)ei[N_EDGES + e];
    int pos = atomicAdd(&cur[dst >> 8], 1);
    bs[pos] = src | ((dst & 255u) << 16);
  }
}

__global__ __launch_bounds__(256) void k_bucket(const int* __restrict__ bstart,
                                                const unsigned int* __restrict__ bs,
                                                unsigned short* __restrict__ nbr,
                                                int* __restrict__ offs,
                                                int* __restrict__ deg) {
  __shared__ int bins[256];
  __shared__ int buf[2][256];
  __shared__ int curs[256];
  int t = threadIdx.x, b = blockIdx.x;
  int s = bstart[b], e = bstart[b + 1];
  bins[t] = 0;
  __syncthreads();
  for (int i = s + t; i < e; i += 256)
    atomicAdd(&bins[(bs[i] >> 16) & 255u], 1);
  __syncthreads();
  int v = bins[t];
  int excl = scan256_excl(v, buf, t);
  int node = b * 256 + t;
  deg[node]  = v;
  offs[node] = s + excl;
  curs[t]    = s + excl;
  __syncthreads();
  for (int i = s + t; i < e; i += 256) {
    unsigned int p = bs[i];
    int pos = atomicAdd(&curs[(p >> 16) & 255u], 1);
    nbr[pos] = (unsigned short)(p & 0xffffu);
  }
}

// ---------------------------------------------------------------------------
// K_GATHER: mean over neighbors (unchanged from R4)
// ---------------------------------------------------------------------------
__global__ __launch_bounds__(256) void k_gather(const unsigned short* __restrict__ h,
                                                const unsigned short* __restrict__ nbr,
                                                const int* __restrict__ offs,
                                                const int* __restrict__ deg,
                                                unsigned short* __restrict__ mn) {
  const int wave = threadIdx.x >> 6;
  const int lane = threadIdx.x & 63;
  const int node = blockIdx.x * 4 + wave;
  if (node >= N_NODES) return;
  const int g = lane >> 4, li = lane & 15;
  const int d  = deg[node];
  const int st = offs[node];
  float a[8] = {0.f, 0.f, 0.f, 0.f, 0.f, 0.f, 0.f, 0.f};
  int n = g;
  for (; n + 4 < d; n += 8) {
    int s0 = nbr[st + n];
    int s1 = nbr[st + n + 4];
    u16x8 v0 = *(const u16x8*)(h + (size_t)s0 * HID + li * 8);
    u16x8 v1 = *(const u16x8*)(h + (size_t)s1 * HID + li * 8);
#pragma unroll
    for (int k = 0; k < 8; k++) a[k] += bf2f(v0[k]) + bf2f(v1[k]);
  }
  if (n < d) {
    int s0 = nbr[st + n];
    u16x8 v0 = *(const u16x8*)(h + (size_t)s0 * HID + li * 8);
#pragma unroll
    for (int k = 0; k < 8; k++) a[k] += bf2f(v0[k]);
  }
#pragma unroll
  for (int k = 0; k < 8; k++) {
    a[k] += __shfl_xor(a[k], 16);
    a[k] += __shfl_xor(a[k], 32);
  }
  if (g == 0) {
    float inv = 1.f / fmaxf((float)d, 1.f);
    u16x8 r;
#pragma unroll
    for (int k = 0; k < 8; k++) r[k] = f2bf(a[k] * inv);
    *(u16x8*)(mn + (size_t)node * HID + li * 8) = r;
  }
}

// ---------------------------------------------------------------------------
// K_SAGE: h2 = [mn|h] @ wcomb^T + lb, in-register LayerNorm+ReLU+pool.
// No LDS in the K-loop; per-block partial pool -> part[block][128].
// ---------------------------------------------------------------------------
__global__ __launch_bounds__(256) void k_sage(const unsigned short* __restrict__ mn,
                                              const unsigned short* __restrict__ h,
                                              const unsigned short* __restrict__ wcomb,
                                              const float* __restrict__ lb,
                                              const float* __restrict__ lg,
                                              const float* __restrict__ lbt,
                                              float* __restrict__ part) {
  __shared__ float red[4][128];
  const int wave = threadIdx.x >> 6, lane = threadIdx.x & 63;
  const int wr0 = blockIdx.x * 128 + wave * 32;
  const int fr = lane & 15, kg = lane >> 4;

  int r0 = wr0 + fr;       if (r0 > N_NODES - 1) r0 = N_NODES - 1;
  int r1 = wr0 + 16 + fr;  if (r1 > N_NODES - 1) r1 = N_NODES - 1;
  const size_t o0 = (size_t)r0 * HID + kg * 8;
  const size_t o1 = (size_t)r1 * HID + kg * 8;
  const unsigned short* pB[8];
#pragma unroll
  for (int n = 0; n < 8; n++)
    pB[n] = wcomb + (size_t)(n * 16 + fr) * 256 + kg * 8;

  f32x4 acc[2][8] = {};

#pragma unroll
  for (int ks = 0; ks < 8; ks++) {
    const int k0 = ks * 32;
    const unsigned short* baseA = (k0 < HID) ? mn : h;
    const int kk = k0 & (HID - 1);
    bf16x8 af0 = *(const bf16x8*)(baseA + o0 + kk);
    bf16x8 af1 = *(const bf16x8*)(baseA + o1 + kk);
    bf16x8 bfv[8];
#pragma unroll
    for (int n = 0; n < 8; n++) bfv[n] = *(const bf16x8*)(pB[n] + k0);
#pragma unroll
    for (int n = 0; n < 8; n++) {
      acc[0][n] = __builtin_amdgcn_mfma_f32_16x16x32_bf16(af0, bfv[n], acc[0][n], 0, 0, 0);
      acc[1][n] = __builtin_amdgcn_mfma_f32_16x16x32_bf16(af1, bfv[n], acc[1][n], 0, 0, 0);
    }
  }

  float lbv[8], lgv[8], lbtv[8];
#pragma unroll
  for (int n = 0; n < 8; n++) {
    lbv[n]  = lb[n * 16 + fr];
    lgv[n]  = lg[n * 16 + fr];
    lbtv[n] = lbt[n * 16 + fr];
  }

  float pool[8] = {};
#pragma unroll
  for (int m = 0; m < 2; m++) {
    float ps[4] = {}, pss[4] = {};
#pragma unroll
    for (int n = 0; n < 8; n++)
#pragma unroll
      for (int i = 0; i < 4; i++) {
        float v = acc[m][n][i] + lbv[n];
        ps[i] += v;
        pss[i] += v * v;
      }
#pragma unroll
    for (int i = 0; i < 4; i++) {
#pragma unroll
      for (int off = 1; off < 16; off <<= 1) {
        ps[i]  += __shfl_xor(ps[i], off);
        pss[i] += __shfl_xor(pss[i], off);
      }
    }
#pragma unroll
    for (int i = 0; i < 4; i++) {
      const int grow = wr0 + m * 16 + kg * 4 + i;
      const float mu = ps[i] * (1.f / HID);
      const float var = pss[i] * (1.f / HID) - mu * mu;
      const float rinv = rsqrtf(var + LN_EPS);
      if (grow < N_NODES) {
#pragma unroll
        for (int n = 0; n < 8; n++) {
          float v = acc[m][n][i] + lbv[n];
          float y = (v - mu) * rinv * lgv[n] + lbtv[n];
          pool[n] += fmaxf(y, 0.f);
        }
      }
    }
  }
#pragma unroll
  for (int n = 0; n < 8; n++) {
    pool[n] += __shfl_xor(pool[n], 16);
    pool[n] += __shfl_xor(pool[n], 32);
  }
  if (kg == 0) {
#pragma unroll
    for (int n = 0; n < 8; n++) red[wave][n * 16 + fr] = pool[n];
  }
  __syncthreads();
  const int t = threadIdx.x;
  if (t < 128)
    part[(size_t)blockIdx.x * 128 + t] =
        red[0][t] + red[1][t] + red[2][t] + red[3][t];
}

// ---------------------------------------------------------------------------
// K_FINAL: reduce part rows, then out = (pool/N) @ out_w^T + out_b
// ---------------------------------------------------------------------------
__global__ __launch_bounds__(128) void k_final(const float* __restrict__ part,
                                               const float* __restrict__ ow,
                                               const float* __restrict__ ob,
                                               float* __restrict__ out) {
  __shared__ float gs[HID];
  int t = threadIdx.x;
  float s = 0.f;
  for (int b = 0; b < MB; b++) s += part[(size_t)b * 128 + t];
  gs[t] = s * (1.f / N_NODES);
  __syncthreads();
  float o = ob[t];
  for (int k = 0; k < HID; k++) o += gs[k] * ow[t * HID + k];
  out[t] = o;
}

// ---------------------------------------------------------------------------
extern "C" void kernel_launch(void* const* d_in, const int* in_sizes, int n_in,
                              void* d_out, int out_size, void* d_ws, size_t ws_size,
                              hipStream_t stream) {
  const float* x   = (const float*)d_in[0];
  const int*   ei  = (const int*)d_in[1];
  const float* pw  = (const float*)d_in[2];
  const float* pb  = (const float*)d_in[3];
  const float* wl  = (const float*)d_in[4];
  const float* lb  = (const float*)d_in[5];
  const float* wr  = (const float*)d_in[6];
  const float* lg  = (const float*)d_in[7];
  const float* lbt = (const float*)d_in[8];
  const float* ow  = (const float*)d_in[9];
  const float* ob  = (const float*)d_in[10];
  float* out = (float*)d_out;

  const int PAD = NBUCK * 256;  // 50176
  unsigned short* h    = (unsigned short*)d_ws;                   // PAD*128 bf16
  unsigned short* mn   = h + (size_t)PAD * HID;                   // PAD*128 bf16
  unsigned int* bsp    = (unsigned int*)(mn + (size_t)PAD * HID); // E packed u32
  unsigned short* nbr  = (unsigned short*)(bsp + N_EDGES);        // E u16
  unsigned short* pwb  = nbr + N_EDGES;                           // 128*1024 bf16
  unsigned short* wcomb= pwb + HID * NODE_DIM;                    // 128*256 bf16
  int* counts = (int*)(wcomb + HID * 256);                        // NBUCK*256
  int* basem  = counts + NBUCK * 256;
  int* btot   = basem + NBUCK * 256;                              // 256
  int* bstart = btot + 256;                                       // 256
  int* offs   = bstart + 256;                                     // PAD
  int* deg    = offs + PAD;                                       // PAD
  float* part = (float*)(deg + PAD);                              // MB*128

  hipLaunchKernelGGL(k_prep,    dim3(640),   dim3(256), 0, stream, pw, wl, wr, pwb, wcomb);
  hipLaunchKernelGGL(k_proj,    dim3(MB),    dim3(256), 0, stream, x, pwb, pb, h);
  hipLaunchKernelGGL(k_hist,    dim3(256),   dim3(256), 0, stream, ei, counts);
  hipLaunchKernelGGL(k_s1,      dim3(NBUCK), dim3(256), 0, stream, counts, basem, btot);
  hipLaunchKernelGGL(k_s2,      dim3(1),     dim3(256), 0, stream, btot, bstart);
  hipLaunchKernelGGL(k_scatter, dim3(256),   dim3(256), 0, stream, ei, basem, bstart, bsp);
  hipLaunchKernelGGL(k_bucket,  dim3(NBUCK), dim3(256), 0, stream, bstart, bsp, nbr, offs, deg);
  hipLaunchKernelGGL(k_gather,  dim3((N_NODES + 3) / 4), dim3(256), 0, stream, h, nbr, offs, deg, mn);
  hipLaunchKernelGGL(k_sage,    dim3(MB),    dim3(256), 0, stream, mn, h, wcomb, lb, lg, lbt, part);
  hipLaunchKernelGGL(k_final,   dim3(1),     dim3(128), 0, stream, part, ow, ob, out);
}